// Round 9
// baseline (3862.629 us; speedup 1.0000x reference)
//
#include <hip/hip_runtime.h>
#include <hip/hip_bf16.h>

// LSTM: T=512, B=64, H=512, L=2.  inputs: x[T,B,H] f32, Wh[L,H,4H], Wx[L,H,4H], bh[L,4H]
// out = concat(out[T,B,H], h_fin[L,B,H], c_fin[L,B,H]) f32.
//
// R9: wave-specialized persistent kernel. 256 WGs = 2 layers x 4 row-quads x
// 32 col-strips; 512 threads = 8 waves. Waves 0-3 ("self side") own the true
// critical cycle: poll self flags -> 16KB sc1 self-h load -> 8-deep Wh MFMA
// chains -> gates -> publish -> flag. Waves 4-7 ("x side") CONCURRENTLY stage
// the other operand (xq for L0: static; h0[t] for L1: 2-stage slack via the
// t=s-2 skew) and compute the Wx partial; they join at the pre-gate barrier.
// R7 failed because both phases ran in program order on the same waves,
// inserting the x-side MALL RT into the self cycle; different waves = max,
// not sum. All cross-WG traffic stays sc1 (MALL-coherent, proven R5/R6);
// per-thread exact-strip flag polls (thread polls only the strip whose
// columns it stages) with s_sleep backoff; no barrier between poll and load.

#define TSEQ 512
#define BATCH 64
#define HID 512
#define H4 2048
#define BH (BATCH * HID)
#define DEPTH 8
#define ZSLOT DEPTH
#define QR 16            // batch rows per quad

typedef short bf16x8 __attribute__((ext_vector_type(8)));
typedef float f32x4 __attribute__((ext_vector_type(4)));
typedef float f32x2 __attribute__((ext_vector_type(2)));
typedef unsigned long long u64;

__device__ __forceinline__ ushort f32_to_bf16(float f) {
    unsigned u = __builtin_bit_cast(unsigned, f);
    u += 0x7FFFu + ((u >> 16) & 1u);   // round-to-nearest-even
    return (ushort)(u >> 16);
}

__device__ __forceinline__ float sigmoid_fast(float x) {
    return 1.f / (1.f + __expf(-x));
}
__device__ __forceinline__ float tanh_fast(float x) {
    return 1.f - 2.f / (1.f + __expf(2.f * x));   // exact at +-inf, ~1e-7 rel err
}

// 16B agent-coherent load (bypasses L1/L2, serviced at MALL)
__device__ __forceinline__ bf16x8 load16_sc1(const ushort* p) {
    bf16x8 v;
    asm volatile("global_load_dwordx4 %0, %1, off sc1" : "=v"(v) : "v"(p));
    return v;
}
// spin until *p >= thr; fast first check, then sleep-backoff (caps MALL traffic)
__device__ __forceinline__ void poll_ge(const int* p, int thr) {
    if (__hip_atomic_load(p, __ATOMIC_RELAXED, __HIP_MEMORY_SCOPE_AGENT) >= thr) return;
    while (__hip_atomic_load(p, __ATOMIC_RELAXED, __HIP_MEMORY_SCOPE_AGENT) < thr)
        __builtin_amdgcn_s_sleep(1);
}

// ---- convert x f32 -> bf16 (vectorized) ----
__global__ __launch_bounds__(256) void convert_x(const float* __restrict__ x,
                                                 ushort* __restrict__ xq) {
    const int n4 = (TSEQ * BATCH * HID) / 4;
    int stride = gridDim.x * blockDim.x;
    for (int i = blockIdx.x * blockDim.x + threadIdx.x; i < n4; i += stride) {
        float4 v = ((const float4*)x)[i];
        ushort4 o;
        o.x = f32_to_bf16(v.x);
        o.y = f32_to_bf16(v.y);
        o.z = f32_to_bf16(v.z);
        o.w = f32_to_bf16(v.w);
        ((ushort4*)xq)[i] = o;
    }
}

// ---- transpose+convert weights: WT[m][n][k] = W[k][n], m: 0=Wx0 1=Wh0 2=Wx1 3=Wh1 ----
__global__ __launch_bounds__(256) void transpose_w(const float* __restrict__ Wh,
                                                   const float* __restrict__ Wx,
                                                   ushort* __restrict__ WT) {
    int bid = blockIdx.x;            // 4 * 8 * 32 = 1024 blocks
    int m  = bid >> 8;               // 0..3
    int kt = (bid >> 5) & 7;         // k tile (64)
    int nt = bid & 31;               // n tile (64)
    const float* src = ((m & 1) ? Wh : Wx) + (size_t)(m >> 1) * (HID * H4);

    __shared__ float tile[64][65];
    int c  = threadIdx.x & 63;
    int r0 = (threadIdx.x >> 6) * 16;
    for (int i = 0; i < 16; ++i) {
        int r = r0 + i;
        tile[r][c] = src[(size_t)(kt * 64 + r) * H4 + nt * 64 + c];
    }
    __syncthreads();
    int k  = threadIdx.x & 63;
    int n0 = (threadIdx.x >> 6) * 16;
    for (int i = 0; i < 16; ++i) {
        int n = n0 + i;
        WT[(size_t)m * (H4 * HID) + (size_t)(nt * 64 + n) * HID + kt * 64 + k] =
            f32_to_bf16(tile[k][n]);
    }
}

// ---- persistent LSTM kernel: 256 WGs x 512 threads ----
__global__ __launch_bounds__(512, 2) void lstm_persistent(
    const ushort* __restrict__ WT,   // [4][2048][512] bf16 (N-major, K contiguous)
    const ushort* __restrict__ xq,   // [512][64][512] bf16
    const float*  __restrict__ bh,   // [2][2048]
    ushort* __restrict__ h0r,        // [DEPTH+1][64][512] bf16 ring (+ zero slot)
    ushort* __restrict__ h1r,        // [DEPTH+1][64][512]
    float*  __restrict__ out,        // d_out
    int*    __restrict__ flags)      // [2][4][32] stage counters, zeroed
{
    const int wg    = blockIdx.x;        // 0..255
    const int layer = wg >> 7;
    const int quad  = (wg >> 5) & 3;
    const int strip = wg & 31;
    const int j0    = strip * 16;
    const int tid   = threadIdx.x;
    const int wave  = tid >> 6;          // 0..7
    const int lane  = tid & 63;
    const int g     = wave & 3;          // gate
    const int side  = wave >> 2;         // 0 = self/Wh (critical), 1 = x/Wx
    const int lo    = lane & 15;
    const int hi    = lane >> 4;

    int* f0 = flags + quad * 32;         // layer0 flags for my quad
    int* f1 = flags + 128 + quad * 32;   // layer1 flags for my quad
    int* selff  = layer ? f1 : f0;
    int* myflag = selff + strip;

    // weights: side 0 -> Wh (m = layer*2+1); side 1 -> Wx (m = layer*2+0)
    const int m = layer * 2 + (side ? 0 : 1);
    const ushort* wp = WT + (size_t)m * (H4 * HID)
                     + (size_t)(g * 512 + j0 + lo) * HID + hi * 8;

    // gate-phase mapping (threads 0..127): row = tid>>3, cols cp,cp+1
    const int grow = tid >> 3;
    const int cp   = (tid & 7) * 2;
    f32x2 bias2[4];
#pragma unroll
    for (int gg = 0; gg < 4; ++gg)
        bias2[gg] = *(const f32x2*)&bh[layer * H4 + gg * 512 + j0 + cp];
    f32x2 creg = (f32x2)(0.f);

    __shared__ __align__(16) ushort ldsS[QR * HID];        // 16 KB self tile
    __shared__ __align__(16) ushort ldsX[QR * HID];        // 16 KB x tile
    __shared__ __align__(16) float  lds_g[4][2][QR][18];   // [gate][side] partials

    // staging map: 256 threads/side, 4 chunks each. kb = column-chunk (16B),
    // rows r0_+4j. Each thread's columns belong to ONE producer strip: kb>>1.
    const int sid    = tid & 255;
    const int kb     = sid & 63;
    const int r0_    = sid >> 6;           // 0..3
    const int myfidx = kb >> 1;            // exact flag index for my columns
    int goff[4], laddr[4];
#pragma unroll
    for (int j = 0; j < 4; ++j) {
        int row = r0_ + 4 * j;
        goff[j]  = (quad * QR + row) * HID + kb * 8;
        laddr[j] = (row << 10) + ((kb << 4) ^ ((row & 15) << 4));
    }

    for (int s = 0; s < TSEQ + 2; ++s) {
        const int t = s - 2 * layer;       // L0: t=s, L1: t=s-2
        const bool act = (t >= 0) && (t < TSEQ);

        if (act) {
            // ============ staging: both sides run CONCURRENTLY ============
            if (side == 0) {
                // critical: self-recurrence h[t-1]
                if (t > 0) {
                    poll_ge(&selff[myfidx], s);
                    if (layer == 0 && s >= 6)
                        poll_ge(&f1[myfidx], s - 5);   // ring anti-dep (slack 5)
                }
                const ushort* S = (layer ? h1r : h0r)
                    + (size_t)((t == 0) ? ZSLOT : ((t - 1) & 7)) * BH;
                bf16x8 u0 = load16_sc1(S + goff[0]);
                bf16x8 u1 = load16_sc1(S + goff[1]);
                bf16x8 u2 = load16_sc1(S + goff[2]);
                bf16x8 u3 = load16_sc1(S + goff[3]);
                asm volatile("s_waitcnt vmcnt(0)" ::: "memory");
                __builtin_amdgcn_sched_barrier(0);
                *(bf16x8*)((char*)ldsS + laddr[0]) = u0;
                *(bf16x8*)((char*)ldsS + laddr[1]) = u1;
                *(bf16x8*)((char*)ldsS + laddr[2]) = u2;
                *(bf16x8*)((char*)ldsS + laddr[3]) = u3;
            } else {
                if (layer == 0) {
                    const ushort* S = xq + (size_t)t * BH;      // static, L2-hot
                    bf16x8 u0 = *(const bf16x8*)(S + goff[0]);
                    bf16x8 u1 = *(const bf16x8*)(S + goff[1]);
                    bf16x8 u2 = *(const bf16x8*)(S + goff[2]);
                    bf16x8 u3 = *(const bf16x8*)(S + goff[3]);
                    *(bf16x8*)((char*)ldsX + laddr[0]) = u0;
                    *(bf16x8*)((char*)ldsX + laddr[1]) = u1;
                    *(bf16x8*)((char*)ldsX + laddr[2]) = u2;
                    *(bf16x8*)((char*)ldsX + laddr[3]) = u3;
                } else {
                    // h0[t] = h0[s-2]: 2 stages of pipeline slack, poll is ~instant
                    poll_ge(&f0[myfidx], s - 1);
                    const ushort* S = h0r + (size_t)((s - 2) & 7) * BH;
                    bf16x8 u0 = load16_sc1(S + goff[0]);
                    bf16x8 u1 = load16_sc1(S + goff[1]);
                    bf16x8 u2 = load16_sc1(S + goff[2]);
                    bf16x8 u3 = load16_sc1(S + goff[3]);
                    asm volatile("s_waitcnt vmcnt(0)" ::: "memory");
                    __builtin_amdgcn_sched_barrier(0);
                    *(bf16x8*)((char*)ldsX + laddr[0]) = u0;
                    *(bf16x8*)((char*)ldsX + laddr[1]) = u1;
                    *(bf16x8*)((char*)ldsX + laddr[2]) = u2;
                    *(bf16x8*)((char*)ldsX + laddr[3]) = u3;
                }
            }
            __syncthreads();               // bar1: tiles staged

            // ============ MFMA: each wave, own side, gate g, K=512 ============
            const char* base = side ? (const char*)ldsX : (const char*)ldsS;
            f32x4 acc0 = (f32x4)(0.f), acc1 = (f32x4)(0.f);
#pragma unroll
            for (int kk = 0; kk < 16; ++kk) {
                const int ad = (lo << 10) + (((kk << 6) + (hi << 4)) ^ ((lo & 15) << 4));
                bf16x8 a = *(const bf16x8*)(base + ad);
                bf16x8 w = *(const bf16x8*)(wp + kk * 32);
                if (kk & 1)
                    acc1 = __builtin_amdgcn_mfma_f32_16x16x32_bf16(a, w, acc1, 0, 0, 0);
                else
                    acc0 = __builtin_amdgcn_mfma_f32_16x16x32_bf16(a, w, acc0, 0, 0, 0);
            }
            f32x4 acc = acc0 + acc1;
            // C/D: col = lane&15 (gate col), row = (lane>>4)*4 + r (batch row)
#pragma unroll
            for (int r = 0; r < 4; ++r)
                lds_g[g][side][hi * 4 + r][lo] = acc[r];
            __syncthreads();               // bar2: partials ready

            // ============ gates (threads 0-127): 2 cells each ============
            f32x2 cn, hn;
            const int slot_w = t & 7;
            const int hoff   = (quad * QR + grow) * HID + j0 + cp;
            if (tid < 128) {
                f32x2 gi = *(const f32x2*)&lds_g[0][0][grow][cp]
                         + *(const f32x2*)&lds_g[0][1][grow][cp] + bias2[0];
                f32x2 gf = *(const f32x2*)&lds_g[1][0][grow][cp]
                         + *(const f32x2*)&lds_g[1][1][grow][cp] + bias2[1];
                f32x2 gg = *(const f32x2*)&lds_g[2][0][grow][cp]
                         + *(const f32x2*)&lds_g[2][1][grow][cp] + bias2[2];
                f32x2 go = *(const f32x2*)&lds_g[3][0][grow][cp]
                         + *(const f32x2*)&lds_g[3][1][grow][cp] + bias2[3];
#pragma unroll
                for (int q = 0; q < 2; ++q) {
                    float si = sigmoid_fast(gi[q]);
                    float sf = sigmoid_fast(gf[q]);
                    float so = sigmoid_fast(go[q]);
                    float tg = tanh_fast(gg[q]);
                    cn[q] = sf * creg[q] + si * tg;
                    hn[q] = so * tanh_fast(cn[q]);
                }
                creg = cn;

                // publish h (sc1), drain this wave's stores before the flag
                ushort* hw = ((layer == 0) ? h0r : h1r) + (size_t)slot_w * BH + hoff;
                unsigned hp = (unsigned)f32_to_bf16(hn[0])
                            | ((unsigned)f32_to_bf16(hn[1]) << 16);
                __hip_atomic_store((unsigned*)hw, hp, __ATOMIC_RELAXED,
                                   __HIP_MEMORY_SCOPE_AGENT);
                asm volatile("s_waitcnt vmcnt(0)" ::: "memory");
            }
            __syncthreads();               // bar3: h drained everywhere
            if (tid == 0)
                __hip_atomic_store(myflag, s + 1, __ATOMIC_RELAXED,
                                   __HIP_MEMORY_SCOPE_AGENT);
            // out / finals AFTER the flag (off the critical path)
            if (tid < 128) {
                if (layer == 1)
                    *(f32x2*)&out[(size_t)t * BH + hoff] = hn;
                if (t == TSEQ - 1) {
                    size_t base2 = (size_t)TSEQ * BH + (size_t)layer * BH + hoff;
                    *(f32x2*)&out[base2] = hn;                      // h_fin
                    *(f32x2*)&out[base2 + 2 * (size_t)BH] = cn;     // c_fin
                }
            }
        } else {
            // inactive stage still publishes (consumers rely on monotone flags)
            if (tid == 0)
                __hip_atomic_store(myflag, s + 1, __ATOMIC_RELAXED,
                                   __HIP_MEMORY_SCOPE_AGENT);
        }
    }
}

extern "C" void kernel_launch(void* const* d_in, const int* in_sizes, int n_in,
                              void* d_out, int out_size, void* d_ws, size_t ws_size,
                              hipStream_t stream) {
    const float* x  = (const float*)d_in[0];
    const float* Wh = (const float*)d_in[1];
    const float* Wx = (const float*)d_in[2];
    const float* bh = (const float*)d_in[3];
    float* out = (float*)d_out;

    char* ws = (char*)d_ws;
    // layout: WT 8MB | xq 32MB | h0r | h1r | flags   (~41.2MB total)
    ushort* WT = (ushort*)ws;
    ushort* xq = (ushort*)(ws + ((size_t)8 << 20));
    char* state = ws + ((size_t)8 << 20) + ((size_t)32 << 20);
    ushort* h0r = (ushort*)state;                          // [DEPTH+1][64][512]
    ushort* h1r = h0r + (size_t)(DEPTH + 1) * BH;
    int* flags  = (int*)(h1r + (size_t)(DEPTH + 1) * BH);  // [2][4][32]
    size_t clear_bytes = (size_t)2 * (DEPTH + 1) * BH * sizeof(ushort) + 256 * sizeof(int);

    hipMemsetAsync(state, 0, clear_bytes, stream);  // zero rings + zero-slots + flags
    convert_x<<<2048, 256, 0, stream>>>(x, xq);
    transpose_w<<<1024, 256, 0, stream>>>(Wh, Wx, WT);
    lstm_persistent<<<256, 512, 0, stream>>>(WT, xq, bh, h0r, h1r, out, flags);
}

// Round 10
// 3282.853 us; speedup vs baseline: 1.1766x; 1.1766x over previous
//
#include <hip/hip_runtime.h>
#include <hip/hip_bf16.h>

// LSTM: T=512, B=64, H=512, L=2.  inputs: x[T,B,H] f32, Wh[L,H,4H], Wx[L,H,4H], bh[L,4H]
// out = concat(out[T,B,H], h_fin[L,B,H], c_fin[L,B,H]) f32.
//
// R10 = R6 (proven best: 256 WGs = 2 layers x 4 row-quads x 32 col-strips,
// combined single-phase staging, sc1 MALL-coherent h+flags, no L2 flushes)
// + three verified deltas:
//  - (row&15)<<4 LDS swizzle (R9-measured: bank conflicts -5x vs R6's row&7)
//  - L1 skew t=s-2: one stage of slack on the h0->L1 edge (poll f0>=s-1
//    passes first check; decouples cross-layer jitter). Flag DAG acyclic:
//    L0 waits f0>=s, f1>=s-5; L1 waits f1>=s, f0>=s-1.
//  - fast sigmoid/tanh via __expf; interleaved acc0/acc1 (8-deep chains)

#define TSEQ 512
#define BATCH 64
#define HID 512
#define H4 2048
#define BH (BATCH * HID)
#define DEPTH 8
#define ZSLOT DEPTH
#define QR 16            // batch rows per quad

typedef short bf16x8 __attribute__((ext_vector_type(8)));
typedef float f32x4 __attribute__((ext_vector_type(4)));
typedef float f32x2 __attribute__((ext_vector_type(2)));
typedef unsigned long long u64;

__device__ __forceinline__ ushort f32_to_bf16(float f) {
    unsigned u = __builtin_bit_cast(unsigned, f);
    u += 0x7FFFu + ((u >> 16) & 1u);   // round-to-nearest-even
    return (ushort)(u >> 16);
}

__device__ __forceinline__ float sigmoid_fast(float x) {
    return 1.f / (1.f + __expf(-x));
}
__device__ __forceinline__ float tanh_fast(float x) {
    return 1.f - 2.f / (1.f + __expf(2.f * x));
}

// 16B agent-coherent load (bypasses L1/L2, serviced at MALL)
__device__ __forceinline__ bf16x8 load16_sc1(const ushort* p) {
    bf16x8 v;
    asm volatile("global_load_dwordx4 %0, %1, off sc1" : "=v"(v) : "v"(p));
    return v;
}

// ---- convert x f32 -> bf16 (vectorized) ----
__global__ __launch_bounds__(256) void convert_x(const float* __restrict__ x,
                                                 ushort* __restrict__ xq) {
    const int n4 = (TSEQ * BATCH * HID) / 4;
    int stride = gridDim.x * blockDim.x;
    for (int i = blockIdx.x * blockDim.x + threadIdx.x; i < n4; i += stride) {
        float4 v = ((const float4*)x)[i];
        ushort4 o;
        o.x = f32_to_bf16(v.x);
        o.y = f32_to_bf16(v.y);
        o.z = f32_to_bf16(v.z);
        o.w = f32_to_bf16(v.w);
        ((ushort4*)xq)[i] = o;
    }
}

// ---- transpose+convert weights: WT[m][n][k] = W[k][n], m: 0=Wx0 1=Wh0 2=Wx1 3=Wh1 ----
__global__ __launch_bounds__(256) void transpose_w(const float* __restrict__ Wh,
                                                   const float* __restrict__ Wx,
                                                   ushort* __restrict__ WT) {
    int bid = blockIdx.x;            // 4 * 8 * 32 = 1024 blocks
    int m  = bid >> 8;               // 0..3
    int kt = (bid >> 5) & 7;         // k tile (64)
    int nt = bid & 31;               // n tile (64)
    const float* src = ((m & 1) ? Wh : Wx) + (size_t)(m >> 1) * (HID * H4);

    __shared__ float tile[64][65];
    int c  = threadIdx.x & 63;
    int r0 = (threadIdx.x >> 6) * 16;
    for (int i = 0; i < 16; ++i) {
        int r = r0 + i;
        tile[r][c] = src[(size_t)(kt * 64 + r) * H4 + nt * 64 + c];
    }
    __syncthreads();
    int k  = threadIdx.x & 63;
    int n0 = (threadIdx.x >> 6) * 16;
    for (int i = 0; i < 16; ++i) {
        int n = n0 + i;
        WT[(size_t)m * (H4 * HID) + (size_t)(nt * 64 + n) * HID + kt * 64 + k] =
            f32_to_bf16(tile[k][n]);
    }
}

// ---- persistent LSTM kernel: 256 WGs x 512 threads ----
__global__ __launch_bounds__(512, 2) void lstm_persistent(
    const ushort* __restrict__ WT,   // [4][2048][512] bf16 (N-major, K contiguous)
    const ushort* __restrict__ xq,   // [512][64][512] bf16
    const float*  __restrict__ bh,   // [2][2048]
    ushort* __restrict__ h0r,        // [DEPTH+1][64][512] bf16 ring (+ zero slot)
    ushort* __restrict__ h1r,        // [DEPTH+1][64][512]
    float*  __restrict__ out,        // d_out
    int*    __restrict__ flags)      // [2][4][32] stage counters, zeroed
{
    const int wg    = blockIdx.x;        // 0..255
    const int layer = wg >> 7;
    const int quad  = (wg >> 5) & 3;
    const int strip = wg & 31;
    const int j0    = strip * 16;
    const int tid   = threadIdx.x;
    const int wave  = tid >> 6;          // 0..7
    const int lane  = tid & 63;
    const int g     = wave & 3;          // gate
    const int kh    = wave >> 2;         // K half (0..1)
    const int lo    = lane & 15;
    const int hi    = lane >> 4;

    int* f0 = flags + quad * 32;         // layer0 flags for my quad
    int* f1 = flags + 128 + quad * 32;   // layer1 flags for my quad
    int* selff  = layer ? f1 : f0;
    int* myflag = selff + strip;

    // weight fragment base pointers (gemm_bt layout, k contiguous-8/lane)
    const ushort* bx = WT + (size_t)(layer * 2 + 0) * (H4 * HID)
                     + (size_t)(g * 512 + j0 + lo) * HID + kh * 256 + hi * 8;
    const ushort* bw = WT + (size_t)(layer * 2 + 1) * (H4 * HID)
                     + (size_t)(g * 512 + j0 + lo) * HID + kh * 256 + hi * 8;

    // gate-phase mapping (threads 0..127): row = tid>>3, cols cp,cp+1
    const int grow = tid >> 3;
    const int cp   = (tid & 7) * 2;
    f32x2 bias2[4];
#pragma unroll
    for (int gg = 0; gg < 4; ++gg)
        bias2[gg] = *(const f32x2*)&bh[layer * H4 + gg * 512 + j0 + cp];
    f32x2 creg = (f32x2)(0.f);

    __shared__ __align__(16) ushort ldsA[2][QR * HID];     // 32 KB: A1, A2 tiles
    __shared__ __align__(16) float  lds_g[4][2][QR][18];   // padded

    // staging: (rows tid>>6, +8) x (64 16B col-chunks); swizzle (row&15)<<4:
    // read phase (16 lanes, fixed hi) then hits 16 DISTINCT chunk slots
    const int rowa = tid >> 6;             // 0..7
    const int rowb = rowa + 8;             // 8..15
    const int kba  = tid & 63;
    const int goffa = (quad * QR + rowa) * HID + kba * 8;
    const int goffb = (quad * QR + rowb) * HID + kba * 8;
    const int laddra = (rowa << 10) + ((kba << 4) ^ ((rowa & 15) << 4));
    const int laddrb = (rowb << 10) + ((kba << 4) ^ ((rowb & 15) << 4));

    for (int s = 0; s < TSEQ + 2; ++s) {
        const int t = s - 2 * layer;       // L0: t=s, L1: t=s-2
        const bool act = (t >= 0) && (t < TSEQ);

        bf16x8 v0, v1, v2, v3;
        if (act && layer == 0) {           // xq static: issue before poll
            const ushort* A1 = xq + (size_t)t * BH;
            v0 = *(const bf16x8*)(A1 + goffa);
            v1 = *(const bf16x8*)(A1 + goffb);
        }

        // ---- stage barrier: 64 pollers, pure spin ----
        if (s > 0) {
            if (tid < 64) {
                const int* f;
                int thr;
                if (tid < 32)          { f = selff + tid;      thr = s; }
                else if (layer == 0)   { f = f1 + (tid - 32);  thr = s - 5; }  // ring anti-dep
                else                   { f = f0 + (tid - 32);  thr = s - 1; }  // slack edge
                while (__hip_atomic_load(f, __ATOMIC_RELAXED,
                                         __HIP_MEMORY_SCOPE_AGENT) < thr) { }
            }
            __syncthreads();
        }

        if (act) {
            if (layer == 0) {
                const ushort* A2 = h0r + (size_t)((s == 0) ? ZSLOT : ((s - 1) & 7)) * BH;
                v2 = load16_sc1(A2 + goffa);
                v3 = load16_sc1(A2 + goffb);
            } else {
                const ushort* A1 = h0r + (size_t)((s - 2) & 7) * BH;          // h0[t]
                v0 = load16_sc1(A1 + goffa);
                v1 = load16_sc1(A1 + goffb);
                const ushort* A2 = h1r + (size_t)((t == 0) ? ZSLOT : ((s - 3) & 7)) * BH;
                v2 = load16_sc1(A2 + goffa);
                v3 = load16_sc1(A2 + goffb);
            }
            asm volatile("s_waitcnt vmcnt(0)" ::: "memory");
            __builtin_amdgcn_sched_barrier(0);
            *(bf16x8*)((char*)&ldsA[0][0] + laddra) = v0;
            *(bf16x8*)((char*)&ldsA[0][0] + laddrb) = v1;
            *(bf16x8*)((char*)&ldsA[1][0] + laddra) = v2;
            *(bf16x8*)((char*)&ldsA[1][0] + laddrb) = v3;
            __syncthreads();

            // MFMA: wave (g, kh); interleaved acc chains (8-deep each)
            f32x4 acc0 = (f32x4)(0.f), acc1 = (f32x4)(0.f);
#pragma unroll
            for (int kk = 0; kk < 8; ++kk) {
                const int ad = (lo << 10)
                             + (((kh << 9) + (kk << 6) + (hi << 4)) ^ ((lo & 15) << 4));
                bf16x8 a1  = *(const bf16x8*)((char*)&ldsA[0][0] + ad);
                bf16x8 a2  = *(const bf16x8*)((char*)&ldsA[1][0] + ad);
                bf16x8 wxf = *(const bf16x8*)(bx + kk * 32);
                bf16x8 whf = *(const bf16x8*)(bw + kk * 32);
                if (kk & 1) {
                    acc1 = __builtin_amdgcn_mfma_f32_16x16x32_bf16(a1, wxf, acc1, 0, 0, 0);
                    acc1 = __builtin_amdgcn_mfma_f32_16x16x32_bf16(a2, whf, acc1, 0, 0, 0);
                } else {
                    acc0 = __builtin_amdgcn_mfma_f32_16x16x32_bf16(a1, wxf, acc0, 0, 0, 0);
                    acc0 = __builtin_amdgcn_mfma_f32_16x16x32_bf16(a2, whf, acc0, 0, 0, 0);
                }
            }
            f32x4 acc = acc0 + acc1;
            // C/D: col = lane&15 (gate col), row = (lane>>4)*4 + r (batch row)
#pragma unroll
            for (int r = 0; r < 4; ++r)
                lds_g[g][kh][hi * 4 + r][lo] = acc[r];
            __syncthreads();

            // ---- gates (threads 0-127): 2 cells each ----
            f32x2 cn, hn;
            const int slot_w = t & 7;
            const int hoff   = (quad * QR + grow) * HID + j0 + cp;
            if (tid < 128) {
                f32x2 gi = *(const f32x2*)&lds_g[0][0][grow][cp]
                         + *(const f32x2*)&lds_g[0][1][grow][cp] + bias2[0];
                f32x2 gf = *(const f32x2*)&lds_g[1][0][grow][cp]
                         + *(const f32x2*)&lds_g[1][1][grow][cp] + bias2[1];
                f32x2 gg = *(const f32x2*)&lds_g[2][0][grow][cp]
                         + *(const f32x2*)&lds_g[2][1][grow][cp] + bias2[2];
                f32x2 go = *(const f32x2*)&lds_g[3][0][grow][cp]
                         + *(const f32x2*)&lds_g[3][1][grow][cp] + bias2[3];
#pragma unroll
                for (int q = 0; q < 2; ++q) {
                    float si = sigmoid_fast(gi[q]);
                    float sf = sigmoid_fast(gf[q]);
                    float so = sigmoid_fast(go[q]);
                    float tg = tanh_fast(gg[q]);
                    cn[q] = sf * creg[q] + si * tg;
                    hn[q] = so * tanh_fast(cn[q]);
                }
                creg = cn;

                // publish h (sc1), drain this wave's stores before the flag
                ushort* hw = ((layer == 0) ? h0r : h1r) + (size_t)slot_w * BH + hoff;
                unsigned hp = (unsigned)f32_to_bf16(hn[0])
                            | ((unsigned)f32_to_bf16(hn[1]) << 16);
                __hip_atomic_store((unsigned*)hw, hp, __ATOMIC_RELAXED,
                                   __HIP_MEMORY_SCOPE_AGENT);
                asm volatile("s_waitcnt vmcnt(0)" ::: "memory");
            }
            __syncthreads();               // h drained everywhere
            if (tid == 0)
                __hip_atomic_store(myflag, s + 1, __ATOMIC_RELAXED,
                                   __HIP_MEMORY_SCOPE_AGENT);
            // out / finals AFTER the flag (off the critical path)
            if (tid < 128) {
                if (layer == 1)
                    *(f32x2*)&out[(size_t)t * BH + hoff] = hn;
                if (t == TSEQ - 1) {
                    size_t base2 = (size_t)TSEQ * BH + (size_t)layer * BH + hoff;
                    *(f32x2*)&out[base2] = hn;                      // h_fin
                    *(f32x2*)&out[base2 + 2 * (size_t)BH] = cn;     // c_fin
                }
            }
        } else {
            // inactive stage still publishes (consumers rely on monotone flags)
            if (tid == 0)
                __hip_atomic_store(myflag, s + 1, __ATOMIC_RELAXED,
                                   __HIP_MEMORY_SCOPE_AGENT);
        }
    }
}

extern "C" void kernel_launch(void* const* d_in, const int* in_sizes, int n_in,
                              void* d_out, int out_size, void* d_ws, size_t ws_size,
                              hipStream_t stream) {
    const float* x  = (const float*)d_in[0];
    const float* Wh = (const float*)d_in[1];
    const float* Wx = (const float*)d_in[2];
    const float* bh = (const float*)d_in[3];
    float* out = (float*)d_out;

    char* ws = (char*)d_ws;
    // layout: WT 8MB | xq 32MB | h0r | h1r | flags   (~41.2MB total)
    ushort* WT = (ushort*)ws;
    ushort* xq = (ushort*)(ws + ((size_t)8 << 20));
    char* state = ws + ((size_t)8 << 20) + ((size_t)32 << 20);
    ushort* h0r = (ushort*)state;                          // [DEPTH+1][64][512]
    ushort* h1r = h0r + (size_t)(DEPTH + 1) * BH;
    int* flags  = (int*)(h1r + (size_t)(DEPTH + 1) * BH);  // [2][4][32]
    size_t clear_bytes = (size_t)2 * (DEPTH + 1) * BH * sizeof(ushort) + 256 * sizeof(int);

    hipMemsetAsync(state, 0, clear_bytes, stream);  // zero rings + zero-slots + flags
    convert_x<<<2048, 256, 0, stream>>>(x, xq);
    transpose_w<<<1024, 256, 0, stream>>>(Wh, Wx, WT);
    lstm_persistent<<<256, 512, 0, stream>>>(WT, xq, bh, h0r, h1r, out, flags);
}

// Round 11
// 2292.016 us; speedup vs baseline: 1.6853x; 1.4323x over previous
//
#include <hip/hip_runtime.h>
#include <hip/hip_bf16.h>

// LSTM: T=512, B=64, H=512, L=2.  inputs: x[T,B,H] f32, Wh[L,H,4H], Wx[L,H,4H], bh[L,4H]
// out = concat(out[T,B,H], h_fin[L,B,H], c_fin[L,B,H]) f32.
//
// R11 = EXACT R6 (best: 2336us; 256 WGs = 2 layers x 4 quads x 32 strips,
// single-phase staging, sc1 MALL-coherent h+flags, L1 skew t=s-1) with ONE
// change: LDS swizzle (row&7)<<4 -> (row&15)<<4 (R9/R10-measured: bank
// conflicts 8.39e7 -> 1.68e7). Bisects the swizzle from R10's other deltas
// (t=s-2 skew, fast-tanh, split acc chains), which together net-regressed.

#define TSEQ 512
#define BATCH 64
#define HID 512
#define H4 2048
#define BH (BATCH * HID)
#define DEPTH 8
#define ZSLOT DEPTH
#define QR 16            // batch rows per quad

typedef short bf16x8 __attribute__((ext_vector_type(8)));
typedef float f32x4 __attribute__((ext_vector_type(4)));
typedef float f32x2 __attribute__((ext_vector_type(2)));
typedef unsigned long long u64;

__device__ __forceinline__ ushort f32_to_bf16(float f) {
    unsigned u = __builtin_bit_cast(unsigned, f);
    u += 0x7FFFu + ((u >> 16) & 1u);   // round-to-nearest-even
    return (ushort)(u >> 16);
}

// 16B agent-coherent load (bypasses L1/L2, serviced at MALL)
__device__ __forceinline__ bf16x8 load16_sc1(const ushort* p) {
    bf16x8 v;
    asm volatile("global_load_dwordx4 %0, %1, off sc1" : "=v"(v) : "v"(p));
    return v;
}

// ---- convert x f32 -> bf16 (vectorized) ----
__global__ __launch_bounds__(256) void convert_x(const float* __restrict__ x,
                                                 ushort* __restrict__ xq) {
    const int n4 = (TSEQ * BATCH * HID) / 4;
    int stride = gridDim.x * blockDim.x;
    for (int i = blockIdx.x * blockDim.x + threadIdx.x; i < n4; i += stride) {
        float4 v = ((const float4*)x)[i];
        ushort4 o;
        o.x = f32_to_bf16(v.x);
        o.y = f32_to_bf16(v.y);
        o.z = f32_to_bf16(v.z);
        o.w = f32_to_bf16(v.w);
        ((ushort4*)xq)[i] = o;
    }
}

// ---- transpose+convert weights: WT[m][n][k] = W[k][n], m: 0=Wx0 1=Wh0 2=Wx1 3=Wh1 ----
__global__ __launch_bounds__(256) void transpose_w(const float* __restrict__ Wh,
                                                   const float* __restrict__ Wx,
                                                   ushort* __restrict__ WT) {
    int bid = blockIdx.x;            // 4 * 8 * 32 = 1024 blocks
    int m  = bid >> 8;               // 0..3
    int kt = (bid >> 5) & 7;         // k tile (64)
    int nt = bid & 31;               // n tile (64)
    const float* src = ((m & 1) ? Wh : Wx) + (size_t)(m >> 1) * (HID * H4);

    __shared__ float tile[64][65];
    int c  = threadIdx.x & 63;
    int r0 = (threadIdx.x >> 6) * 16;
    for (int i = 0; i < 16; ++i) {
        int r = r0 + i;
        tile[r][c] = src[(size_t)(kt * 64 + r) * H4 + nt * 64 + c];
    }
    __syncthreads();
    int k  = threadIdx.x & 63;
    int n0 = (threadIdx.x >> 6) * 16;
    for (int i = 0; i < 16; ++i) {
        int n = n0 + i;
        WT[(size_t)m * (H4 * HID) + (size_t)(nt * 64 + n) * HID + kt * 64 + k] =
            f32_to_bf16(tile[k][n]);
    }
}

// ---- persistent LSTM kernel: 256 WGs x 512 threads ----
__global__ __launch_bounds__(512, 2) void lstm_persistent(
    const ushort* __restrict__ WT,   // [4][2048][512] bf16 (N-major, K contiguous)
    const ushort* __restrict__ xq,   // [512][64][512] bf16
    const float*  __restrict__ bh,   // [2][2048]
    ushort* __restrict__ h0r,        // [DEPTH+1][64][512] bf16 ring (+ zero slot)
    ushort* __restrict__ h1r,        // [DEPTH+1][64][512]
    float*  __restrict__ out,        // d_out
    int*    __restrict__ flags)      // [2][4][32] stage counters, zeroed
{
    const int wg    = blockIdx.x;        // 0..255
    const int layer = wg >> 7;
    const int quad  = (wg >> 5) & 3;
    const int strip = wg & 31;
    const int j0    = strip * 16;
    const int tid   = threadIdx.x;
    const int wave  = tid >> 6;          // 0..7
    const int lane  = tid & 63;
    const int g     = wave & 3;          // gate
    const int kh    = wave >> 2;         // K half (0..1)
    const int lo    = lane & 15;
    const int hi    = lane >> 4;

    // weight fragment base pointers (gemm_bt layout, k contiguous-8/lane)
    const ushort* bx = WT + (size_t)(layer * 2 + 0) * (H4 * HID)
                     + (size_t)(g * 512 + j0 + lo) * HID + kh * 256 + hi * 8;
    const ushort* bw = WT + (size_t)(layer * 2 + 1) * (H4 * HID)
                     + (size_t)(g * 512 + j0 + lo) * HID + kh * 256 + hi * 8;
    bf16x8 wx[8], wh[8];
#pragma unroll
    for (int kk = 0; kk < 8; ++kk) {
        wx[kk] = *(const bf16x8*)(bx + kk * 32);
        wh[kk] = *(const bf16x8*)(bw + kk * 32);
    }
#pragma unroll
    for (int kk = 0; kk < 8; ++kk) {
        asm volatile("" : "+v"(wx[kk]));
        asm volatile("" : "+v"(wh[kk]));
    }

    // gate-phase mapping (threads 0..127): row = tid>>3 (0..15), cols cp,cp+1
    const int grow = tid >> 3;
    const int cp   = (tid & 7) * 2;
    f32x2 bias2[4];
#pragma unroll
    for (int gg = 0; gg < 4; ++gg)
        bias2[gg] = *(const f32x2*)&bh[layer * H4 + gg * 512 + j0 + cp];
    f32x2 creg = (f32x2)(0.f);

    __shared__ __align__(16) ushort ldsA[2][QR * HID];     // 32 KB: A1, A2 tiles
    __shared__ __align__(16) float  lds_g[4][2][QR][18];   // padded

    // staging: (rows tid>>6, +8) x (64 16B col-chunks); swizzle (row&15)<<4:
    // MFMA read (16 lanes lo=0..15, fixed hi) hits 16 DISTINCT 16B slots
    // (R6's (row&7)<<4 aliased lo and lo+8 -> 4-way, measured 8.4e7 conflicts)
    const int rowa = tid >> 6;             // 0..7
    const int rowb = rowa + 8;             // 8..15
    const int kba  = tid & 63;
    const int goffa = (quad * QR + rowa) * HID + kba * 8;
    const int goffb = (quad * QR + rowb) * HID + kba * 8;
    const int laddra = ((rowa << 10) + (kba << 4)) ^ ((rowa & 15) << 4);
    const int laddrb = ((rowb << 10) + (kba << 4)) ^ ((rowb & 15) << 4);

    for (int s = 0; s <= TSEQ; ++s) {
        const int t = s - layer;
        const bool active = (t >= 0 && t < TSEQ);

        bf16x8 v0, v1, v2, v3;
        // xq is static: issue its loads BEFORE the poll (overlaps observe latency)
        if (active && layer == 0) {
            const ushort* A1 = xq + (size_t)t * BH;
            v0 = *(const bf16x8*)(A1 + goffa);
            v1 = *(const bf16x8*)(A1 + goffb);
        }

        // ---- stage barrier: 64 pollers, pure spin ----
        if (s > 0) {
            if (tid < 64) {
                int idx, thr;
                if (tid < 32) { idx = quad * 32 + tid;              thr = s; }
                else          { idx = 128 + quad * 32 + (tid - 32);
                                thr = (layer == 0) ? s - (DEPTH - 2) : s; }
                const int* f = &flags[idx];
                while (__hip_atomic_load(f, __ATOMIC_RELAXED,
                                         __HIP_MEMORY_SCOPE_AGENT) < thr) { }
            }
            __syncthreads();
        }

        if (active) {
            const int pslot = (t == 0) ? ZSLOT : ((t - 1) & (DEPTH - 1));
            if (layer == 0) {
                const ushort* A2 = h0r + (size_t)pslot * BH;              // coherent
                v2 = load16_sc1(A2 + goffa);
                v3 = load16_sc1(A2 + goffb);
            } else {
                const ushort* A1 = h0r + (size_t)(t & (DEPTH - 1)) * BH;  // coherent
                v0 = load16_sc1(A1 + goffa);
                v1 = load16_sc1(A1 + goffb);
                const ushort* A2 = h1r + (size_t)pslot * BH;              // coherent
                v2 = load16_sc1(A2 + goffa);
                v3 = load16_sc1(A2 + goffb);
            }
            asm volatile("s_waitcnt vmcnt(0)" ::: "memory");
            __builtin_amdgcn_sched_barrier(0);
            *(bf16x8*)((char*)&ldsA[0][0] + laddra) = v0;
            *(bf16x8*)((char*)&ldsA[0][0] + laddrb) = v1;
            *(bf16x8*)((char*)&ldsA[1][0] + laddra) = v2;
            *(bf16x8*)((char*)&ldsA[1][0] + laddrb) = v3;
            __syncthreads();

            // MFMA: wave (g, kh) computes 16x16 gate tile, K-half kh
            f32x4 acc = (f32x4)(0.f);
#pragma unroll
            for (int kk = 0; kk < 8; ++kk) {
                const int kb2 = kh * 512 + kk * 64 + hi * 16;        // byte offset in row
                const int ad  = ((lo << 10) + kb2) ^ ((lo & 15) << 4);
                bf16x8 a1 = *(const bf16x8*)((char*)&ldsA[0][0] + ad);
                bf16x8 a2 = *(const bf16x8*)((char*)&ldsA[1][0] + ad);
                acc = __builtin_amdgcn_mfma_f32_16x16x32_bf16(a1, wx[kk], acc, 0, 0, 0);
                acc = __builtin_amdgcn_mfma_f32_16x16x32_bf16(a2, wh[kk], acc, 0, 0, 0);
            }
            // C/D layout: col = lane&15, row = (lane>>4)*4 + r
#pragma unroll
            for (int r = 0; r < 4; ++r)
                lds_g[g][kh][hi * 4 + r][lo] = acc[r];
            __syncthreads();

            // gates (2 waves): 2 cells per thread
            f32x2 cn, hn;
            if (tid < 128) {
                f32x2 gi = *(const f32x2*)&lds_g[0][0][grow][cp]
                         + *(const f32x2*)&lds_g[0][1][grow][cp] + bias2[0];
                f32x2 gf = *(const f32x2*)&lds_g[1][0][grow][cp]
                         + *(const f32x2*)&lds_g[1][1][grow][cp] + bias2[1];
                f32x2 gg = *(const f32x2*)&lds_g[2][0][grow][cp]
                         + *(const f32x2*)&lds_g[2][1][grow][cp] + bias2[2];
                f32x2 go = *(const f32x2*)&lds_g[3][0][grow][cp]
                         + *(const f32x2*)&lds_g[3][1][grow][cp] + bias2[3];
#pragma unroll
                for (int q = 0; q < 2; ++q) {
                    float si = 1.f / (1.f + __expf(-gi[q]));
                    float sf = 1.f / (1.f + __expf(-gf[q]));
                    float so = 1.f / (1.f + __expf(-go[q]));
                    float tg = tanhf(gg[q]);
                    cn[q] = sf * creg[q] + si * tg;
                    hn[q] = so * tanhf(cn[q]);
                }
                creg = cn;

                // publish h (sc1, 2 bf16 packed), drain this wave's stores
                ushort* hw = ((layer == 0) ? h0r : h1r)
                           + (size_t)(t & (DEPTH - 1)) * BH
                           + (size_t)(quad * QR + grow) * HID + j0 + cp;
                unsigned hp = (unsigned)f32_to_bf16(hn[0])
                            | ((unsigned)f32_to_bf16(hn[1]) << 16);
                __hip_atomic_store((unsigned*)hw, hp, __ATOMIC_RELAXED,
                                   __HIP_MEMORY_SCOPE_AGENT);
                asm volatile("s_waitcnt vmcnt(0)" ::: "memory");
            }
            __syncthreads();          // gate waves drained -> flag is safe
            if (tid == 0)
                __hip_atomic_store(&flags[layer * 128 + quad * 32 + strip], s + 1,
                                   __ATOMIC_RELAXED, __HIP_MEMORY_SCOPE_AGENT);
            // out / finals AFTER the flag (off the critical path)
            if (tid < 128) {
                if (layer == 1)
                    *(f32x2*)&out[(size_t)t * BH + (size_t)(quad * QR + grow) * HID
                                  + j0 + cp] = hn;
                if (t == TSEQ - 1) {
                    size_t base = (size_t)TSEQ * BH + (size_t)layer * BH
                                + (size_t)(quad * QR + grow) * HID + j0 + cp;
                    *(f32x2*)&out[base] = hn;                       // h_fin
                    *(f32x2*)&out[base + 2 * (size_t)BH] = cn;      // c_fin
                }
            }
        } else {
            // inactive stage still publishes (consumers rely on monotone flags)
            if (tid == 0)
                __hip_atomic_store(&flags[layer * 128 + quad * 32 + strip], s + 1,
                                   __ATOMIC_RELAXED, __HIP_MEMORY_SCOPE_AGENT);
        }
    }
}

extern "C" void kernel_launch(void* const* d_in, const int* in_sizes, int n_in,
                              void* d_out, int out_size, void* d_ws, size_t ws_size,
                              hipStream_t stream) {
    const float* x  = (const float*)d_in[0];
    const float* Wh = (const float*)d_in[1];
    const float* Wx = (const float*)d_in[2];
    const float* bh = (const float*)d_in[3];
    float* out = (float*)d_out;

    char* ws = (char*)d_ws;
    // layout: WT 8MB | xq 32MB | h0r | h1r | flags   (~41.2MB total)
    ushort* WT = (ushort*)ws;
    ushort* xq = (ushort*)(ws + ((size_t)8 << 20));
    char* state = ws + ((size_t)8 << 20) + ((size_t)32 << 20);
    ushort* h0r = (ushort*)state;                          // [DEPTH+1][64][512]
    ushort* h1r = h0r + (size_t)(DEPTH + 1) * BH;
    int* flags  = (int*)(h1r + (size_t)(DEPTH + 1) * BH);  // [2][4][32]
    size_t clear_bytes = (size_t)2 * (DEPTH + 1) * BH * sizeof(ushort) + 256 * sizeof(int);

    hipMemsetAsync(state, 0, clear_bytes, stream);  // zero rings + zero-slots + flags
    convert_x<<<2048, 256, 0, stream>>>(x, xq);
    transpose_w<<<1024, 256, 0, stream>>>(Wh, Wx, WT);
    lstm_persistent<<<256, 512, 0, stream>>>(WT, xq, bh, h0r, h1r, out, flags);
}

// Round 12
// 2119.306 us; speedup vs baseline: 1.8226x; 1.0815x over previous
//
#include <hip/hip_runtime.h>
#include <hip/hip_bf16.h>

// LSTM: T=512, B=64, H=512, L=2.  inputs: x[T,B,H] f32, Wh[L,H,4H], Wx[L,H,4H], bh[L,4H]
// out = concat(out[T,B,H], h_fin[L,B,H], c_fin[L,B,H]) f32.
//
// R12 = R11 protocol (sc1 MALL-coherent h+flags, skew t=s-1, (row&15) swizzle,
// flag DAG: self>=s, L0 anti-dep f1>=s-6, L1 x-edge f0>=s) with HALF the WGs:
// 128 WGs = 2 layers x 4 quads x 16 strips of 32 columns, 1024 threads each.
// Purpose: the 32x read amplification (every strip re-reads its quad's full
// 16KB h tile) made 8MB/stage of sc1 MALL reads; 16 strips -> 4MB/stage and
// half the flag-poll fan-in. Per-WG volume unchanged (32KB), per-thread load
// volume halves (2x16B). MFMA: 16 waves = gate(4) x col-tile(2) x K-half(2),
// 16 MFMAs each (same per-wave work as R11).

#define TSEQ 512
#define BATCH 64
#define HID 512
#define H4 2048
#define BH (BATCH * HID)
#define DEPTH 8
#define ZSLOT DEPTH
#define QR 16            // batch rows per quad
#define NSTRIP 16        // strips per (layer,quad); 32 cols each

typedef short bf16x8 __attribute__((ext_vector_type(8)));
typedef float f32x4 __attribute__((ext_vector_type(4)));
typedef float f32x2 __attribute__((ext_vector_type(2)));
typedef unsigned long long u64;

__device__ __forceinline__ ushort f32_to_bf16(float f) {
    unsigned u = __builtin_bit_cast(unsigned, f);
    u += 0x7FFFu + ((u >> 16) & 1u);   // round-to-nearest-even
    return (ushort)(u >> 16);
}

// 16B agent-coherent load (bypasses L1/L2, serviced at MALL)
__device__ __forceinline__ bf16x8 load16_sc1(const ushort* p) {
    bf16x8 v;
    asm volatile("global_load_dwordx4 %0, %1, off sc1" : "=v"(v) : "v"(p));
    return v;
}

// ---- convert x f32 -> bf16 (vectorized) ----
__global__ __launch_bounds__(256) void convert_x(const float* __restrict__ x,
                                                 ushort* __restrict__ xq) {
    const int n4 = (TSEQ * BATCH * HID) / 4;
    int stride = gridDim.x * blockDim.x;
    for (int i = blockIdx.x * blockDim.x + threadIdx.x; i < n4; i += stride) {
        float4 v = ((const float4*)x)[i];
        ushort4 o;
        o.x = f32_to_bf16(v.x);
        o.y = f32_to_bf16(v.y);
        o.z = f32_to_bf16(v.z);
        o.w = f32_to_bf16(v.w);
        ((ushort4*)xq)[i] = o;
    }
}

// ---- transpose+convert weights: WT[m][n][k] = W[k][n], m: 0=Wx0 1=Wh0 2=Wx1 3=Wh1 ----
__global__ __launch_bounds__(256) void transpose_w(const float* __restrict__ Wh,
                                                   const float* __restrict__ Wx,
                                                   ushort* __restrict__ WT) {
    int bid = blockIdx.x;            // 4 * 8 * 32 = 1024 blocks
    int m  = bid >> 8;               // 0..3
    int kt = (bid >> 5) & 7;         // k tile (64)
    int nt = bid & 31;               // n tile (64)
    const float* src = ((m & 1) ? Wh : Wx) + (size_t)(m >> 1) * (HID * H4);

    __shared__ float tile[64][65];
    int c  = threadIdx.x & 63;
    int r0 = (threadIdx.x >> 6) * 16;
    for (int i = 0; i < 16; ++i) {
        int r = r0 + i;
        tile[r][c] = src[(size_t)(kt * 64 + r) * H4 + nt * 64 + c];
    }
    __syncthreads();
    int k  = threadIdx.x & 63;
    int n0 = (threadIdx.x >> 6) * 16;
    for (int i = 0; i < 16; ++i) {
        int n = n0 + i;
        WT[(size_t)m * (H4 * HID) + (size_t)(nt * 64 + n) * HID + kt * 64 + k] =
            f32_to_bf16(tile[k][n]);
    }
}

// ---- persistent LSTM kernel: 128 WGs x 1024 threads ----
__global__ __launch_bounds__(1024, 4) void lstm_persistent(
    const ushort* __restrict__ WT,   // [4][2048][512] bf16 (N-major, K contiguous)
    const ushort* __restrict__ xq,   // [512][64][512] bf16
    const float*  __restrict__ bh,   // [2][2048]
    ushort* __restrict__ h0r,        // [DEPTH+1][64][512] bf16 ring (+ zero slot)
    ushort* __restrict__ h1r,        // [DEPTH+1][64][512]
    float*  __restrict__ out,        // d_out
    int*    __restrict__ flags)      // [2][4][16] stage counters, zeroed
{
    const int wg    = blockIdx.x;        // 0..127
    const int layer = wg >> 6;
    const int quad  = (wg >> 4) & 3;
    const int strip = wg & 15;           // 32-column strip
    const int j0    = strip * 32;
    const int tid   = threadIdx.x;
    const int wave  = tid >> 6;          // 0..15
    const int lane  = tid & 63;
    const int g     = wave & 3;          // gate
    const int ch    = (wave >> 2) & 1;   // col-tile half (16 cols)
    const int kh    = wave >> 3;         // K half (0..1)
    const int lo    = lane & 15;
    const int hi    = lane >> 4;

    int* f0 = flags + quad * NSTRIP;          // layer0 flags, my quad
    int* f1 = flags + 64 + quad * NSTRIP;     // layer1 flags, my quad
    int* selff  = layer ? f1 : f0;
    int* otherf = layer ? f0 : f1;
    int* myflag = selff + strip;

    // weight fragment base pointers (gemm_bt layout, k contiguous-8/lane)
    const ushort* bx = WT + (size_t)(layer * 2 + 0) * (H4 * HID)
                     + (size_t)(g * 512 + j0 + ch * 16 + lo) * HID + kh * 256 + hi * 8;
    const ushort* bw = WT + (size_t)(layer * 2 + 1) * (H4 * HID)
                     + (size_t)(g * 512 + j0 + ch * 16 + lo) * HID + kh * 256 + hi * 8;
    bf16x8 wx[8], wh[8];
#pragma unroll
    for (int kk = 0; kk < 8; ++kk) {
        wx[kk] = *(const bf16x8*)(bx + kk * 32);
        wh[kk] = *(const bf16x8*)(bw + kk * 32);
    }
#pragma unroll
    for (int kk = 0; kk < 8; ++kk) {
        asm volatile("" : "+v"(wx[kk]));
        asm volatile("" : "+v"(wh[kk]));
    }

    // gate-phase mapping (threads 0..255): row = tid>>4 (0..15), cols cp,cp+1 (0..31)
    const int grow = tid >> 4;
    const int cp   = (tid & 15) * 2;
    f32x2 bias2[4];
#pragma unroll
    for (int gg = 0; gg < 4; ++gg)
        bias2[gg] = *(const f32x2*)&bh[layer * H4 + gg * 512 + j0 + cp];
    f32x2 creg = (f32x2)(0.f);

    __shared__ __align__(16) ushort ldsA[2][QR * HID];      // 32 KB: A1, A2 tiles
    __shared__ __align__(16) float  lds_g[4][2][QR][34];    // padded (32+2)

    // staging: 1024 threads, 1 chunk per matrix: row = tid>>6, kba = tid&63
    const int row  = tid >> 6;             // 0..15
    const int kba  = tid & 63;
    const int goff  = (quad * QR + row) * HID + kba * 8;
    const int laddr = ((row << 10) + (kba << 4)) ^ ((row & 15) << 4);

    for (int s = 0; s <= TSEQ; ++s) {
        const int t = s - layer;
        const bool active = (t >= 0 && t < TSEQ);

        bf16x8 v0, v1;
        // xq is static: issue its load BEFORE the poll (overlaps observe latency)
        if (active && layer == 0) {
            v0 = *(const bf16x8*)(xq + (size_t)t * BH + goff);
        }

        // ---- stage barrier: 32 pollers, pure spin ----
        if (s > 0) {
            if (tid < 32) {
                const int* f;
                int thr;
                if (tid < NSTRIP)      { f = selff + tid;            thr = s; }
                else if (layer == 0)   { f = otherf + (tid - NSTRIP); thr = s - (DEPTH - 2); }
                else                   { f = otherf + (tid - NSTRIP); thr = s; }
                while (__hip_atomic_load(f, __ATOMIC_RELAXED,
                                         __HIP_MEMORY_SCOPE_AGENT) < thr) { }
            }
            __syncthreads();
        }

        if (active) {
            const int pslot = (t == 0) ? ZSLOT : ((t - 1) & (DEPTH - 1));
            if (layer == 0) {
                v1 = load16_sc1(h0r + (size_t)pslot * BH + goff);          // h0[t-1]
            } else {
                v0 = load16_sc1(h0r + (size_t)(t & (DEPTH - 1)) * BH + goff);  // h0[t]
                v1 = load16_sc1(h1r + (size_t)pslot * BH + goff);          // h1[t-1]
            }
            asm volatile("s_waitcnt vmcnt(0)" ::: "memory");
            __builtin_amdgcn_sched_barrier(0);
            *(bf16x8*)((char*)&ldsA[0][0] + laddr) = v0;
            *(bf16x8*)((char*)&ldsA[1][0] + laddr) = v1;
            __syncthreads();

            // MFMA: wave (g, ch, kh) computes 16x16 tile (cols ch*16), K-half kh
            f32x4 acc = (f32x4)(0.f);
#pragma unroll
            for (int kk = 0; kk < 8; ++kk) {
                const int kb2 = kh * 512 + kk * 64 + hi * 16;        // byte offset in row
                const int ad  = ((lo << 10) + kb2) ^ ((lo & 15) << 4);
                bf16x8 a1 = *(const bf16x8*)((char*)&ldsA[0][0] + ad);
                bf16x8 a2 = *(const bf16x8*)((char*)&ldsA[1][0] + ad);
                acc = __builtin_amdgcn_mfma_f32_16x16x32_bf16(a1, wx[kk], acc, 0, 0, 0);
                acc = __builtin_amdgcn_mfma_f32_16x16x32_bf16(a2, wh[kk], acc, 0, 0, 0);
            }
            // C/D layout: col = lane&15, row = (lane>>4)*4 + r
#pragma unroll
            for (int r = 0; r < 4; ++r)
                lds_g[g][kh][hi * 4 + r][ch * 16 + lo] = acc[r];
            __syncthreads();

            // gates (threads 0..255): 2 cells per thread
            f32x2 cn, hn;
            if (tid < 256) {
                f32x2 gi = *(const f32x2*)&lds_g[0][0][grow][cp]
                         + *(const f32x2*)&lds_g[0][1][grow][cp] + bias2[0];
                f32x2 gf = *(const f32x2*)&lds_g[1][0][grow][cp]
                         + *(const f32x2*)&lds_g[1][1][grow][cp] + bias2[1];
                f32x2 gg = *(const f32x2*)&lds_g[2][0][grow][cp]
                         + *(const f32x2*)&lds_g[2][1][grow][cp] + bias2[2];
                f32x2 go = *(const f32x2*)&lds_g[3][0][grow][cp]
                         + *(const f32x2*)&lds_g[3][1][grow][cp] + bias2[3];
#pragma unroll
                for (int q = 0; q < 2; ++q) {
                    float si = 1.f / (1.f + __expf(-gi[q]));
                    float sf = 1.f / (1.f + __expf(-gf[q]));
                    float so = 1.f / (1.f + __expf(-go[q]));
                    float tg = tanhf(gg[q]);
                    cn[q] = sf * creg[q] + si * tg;
                    hn[q] = so * tanhf(cn[q]);
                }
                creg = cn;

                // publish h (sc1, 2 bf16 packed), drain this wave's stores
                ushort* hw = ((layer == 0) ? h0r : h1r)
                           + (size_t)(t & (DEPTH - 1)) * BH
                           + (size_t)(quad * QR + grow) * HID + j0 + cp;
                unsigned hp = (unsigned)f32_to_bf16(hn[0])
                            | ((unsigned)f32_to_bf16(hn[1]) << 16);
                __hip_atomic_store((unsigned*)hw, hp, __ATOMIC_RELAXED,
                                   __HIP_MEMORY_SCOPE_AGENT);
                asm volatile("s_waitcnt vmcnt(0)" ::: "memory");
            }
            __syncthreads();          // gate waves drained -> flag is safe
            if (tid == 0)
                __hip_atomic_store(myflag, s + 1, __ATOMIC_RELAXED,
                                   __HIP_MEMORY_SCOPE_AGENT);
            // out / finals AFTER the flag (off the critical path)
            if (tid < 256) {
                const int hoff = (quad * QR + grow) * HID + j0 + cp;
                if (layer == 1)
                    *(f32x2*)&out[(size_t)t * BH + hoff] = hn;
                if (t == TSEQ - 1) {
                    size_t base = (size_t)TSEQ * BH + (size_t)layer * BH + hoff;
                    *(f32x2*)&out[base] = hn;                       // h_fin
                    *(f32x2*)&out[base + 2 * (size_t)BH] = cn;      // c_fin
                }
            }
        } else {
            // inactive stage still publishes (consumers rely on monotone flags)
            if (tid == 0)
                __hip_atomic_store(myflag, s + 1, __ATOMIC_RELAXED,
                                   __HIP_MEMORY_SCOPE_AGENT);
        }
    }
}

extern "C" void kernel_launch(void* const* d_in, const int* in_sizes, int n_in,
                              void* d_out, int out_size, void* d_ws, size_t ws_size,
                              hipStream_t stream) {
    const float* x  = (const float*)d_in[0];
    const float* Wh = (const float*)d_in[1];
    const float* Wx = (const float*)d_in[2];
    const float* bh = (const float*)d_in[3];
    float* out = (float*)d_out;

    char* ws = (char*)d_ws;
    // layout: WT 8MB | xq 32MB | h0r | h1r | flags   (~41.2MB total)
    ushort* WT = (ushort*)ws;
    ushort* xq = (ushort*)(ws + ((size_t)8 << 20));
    char* state = ws + ((size_t)8 << 20) + ((size_t)32 << 20);
    ushort* h0r = (ushort*)state;                          // [DEPTH+1][64][512]
    ushort* h1r = h0r + (size_t)(DEPTH + 1) * BH;
    int* flags  = (int*)(h1r + (size_t)(DEPTH + 1) * BH);  // [2][4][16]
    size_t clear_bytes = (size_t)2 * (DEPTH + 1) * BH * sizeof(ushort) + 128 * sizeof(int);

    hipMemsetAsync(state, 0, clear_bytes, stream);  // zero rings + zero-slots + flags
    convert_x<<<2048, 256, 0, stream>>>(x, xq);
    transpose_w<<<1024, 256, 0, stream>>>(Wh, Wx, WT);
    lstm_persistent<<<128, 1024, 0, stream>>>(WT, xq, bh, h0r, h1r, out, flags);
}

// Round 13
// 1831.948 us; speedup vs baseline: 2.1085x; 1.1569x over previous
//
#include <hip/hip_runtime.h>
#include <hip/hip_bf16.h>

// LSTM: T=512, B=64, H=512, L=2.  inputs: x[T,B,H] f32, Wh[L,H,4H], Wx[L,H,4H], bh[L,4H]
// out = concat(out[T,B,H], h_fin[L,B,H], c_fin[L,B,H]) f32.
//
// R13 = R12 topology (128 WGs = 2 layers x 4 quads x 16 strips x 1024 thr,
// sc1 MALL-coherent exchange, (row&15) swizzle, skew t=s-1) with TAGGED h:
// h stored as 8B records [2 bf16 | tag=t+1] via relaxed sc1 atomics (8B
// aligned stores are single-copy atomic). Consumers retry-load records until
// tags match the expected generation - data IS the flag. Removes the
// writer's vmcnt-drain, the flag store, and the separate poll RT from the
// critical cycle (R12: ~2 extra MALL RTs per stage). Ring safety: tags kill
// stale reads; clobber-before-read prevented by self-sync (stage s implies
// all strips finished s-1; overwrite is gen s-8) + L1 progress flag polled
// by L0 with slack 6 (cheap, no drain). Rings+flags memset every launch.

#define TSEQ 512
#define BATCH 64
#define HID 512
#define H4 2048
#define BH (BATCH * HID)
#define DEPTH 8
#define QR 16            // batch rows per quad
#define NSTRIP 16        // strips per (layer,quad); 32 cols each
#define RPR 256          // records per row (HID/2)

typedef short bf16x8 __attribute__((ext_vector_type(8)));
typedef float f32x4 __attribute__((ext_vector_type(4)));
typedef float f32x2 __attribute__((ext_vector_type(2)));
typedef unsigned long long u64;
typedef u64 u64x2 __attribute__((ext_vector_type(2)));

__device__ __forceinline__ ushort f32_to_bf16(float f) {
    unsigned u = __builtin_bit_cast(unsigned, f);
    u += 0x7FFFu + ((u >> 16) & 1u);   // round-to-nearest-even
    return (ushort)(u >> 16);
}

// retry-load 4 tagged records (32B) until all tags == tag; returns 8 bf16
__device__ __forceinline__ bf16x8 load_tagged(const u64* p, unsigned tag) {
    u64x2 a, b;
    for (;;) {
        asm volatile("global_load_dwordx4 %0, %2, off sc1\n\t"
                     "global_load_dwordx4 %1, %3, off sc1\n\t"
                     "s_waitcnt vmcnt(0)"
                     : "=&v"(a), "=&v"(b) : "v"(p), "v"(p + 2) : "memory");
        if ((unsigned)(a.x >> 32) == tag && (unsigned)(a.y >> 32) == tag &&
            (unsigned)(b.x >> 32) == tag && (unsigned)(b.y >> 32) == tag) break;
        __builtin_amdgcn_s_sleep(1);
    }
    union { unsigned u[4]; bf16x8 v; } r;
    r.u[0] = (unsigned)a.x; r.u[1] = (unsigned)a.y;
    r.u[2] = (unsigned)b.x; r.u[3] = (unsigned)b.y;
    return r.v;
}

// ---- convert x f32 -> bf16 (vectorized) ----
__global__ __launch_bounds__(256) void convert_x(const float* __restrict__ x,
                                                 ushort* __restrict__ xq) {
    const int n4 = (TSEQ * BATCH * HID) / 4;
    int stride = gridDim.x * blockDim.x;
    for (int i = blockIdx.x * blockDim.x + threadIdx.x; i < n4; i += stride) {
        float4 v = ((const float4*)x)[i];
        ushort4 o;
        o.x = f32_to_bf16(v.x);
        o.y = f32_to_bf16(v.y);
        o.z = f32_to_bf16(v.z);
        o.w = f32_to_bf16(v.w);
        ((ushort4*)xq)[i] = o;
    }
}

// ---- transpose+convert weights: WT[m][n][k] = W[k][n], m: 0=Wx0 1=Wh0 2=Wx1 3=Wh1 ----
__global__ __launch_bounds__(256) void transpose_w(const float* __restrict__ Wh,
                                                   const float* __restrict__ Wx,
                                                   ushort* __restrict__ WT) {
    int bid = blockIdx.x;            // 4 * 8 * 32 = 1024 blocks
    int m  = bid >> 8;               // 0..3
    int kt = (bid >> 5) & 7;         // k tile (64)
    int nt = bid & 31;               // n tile (64)
    const float* src = ((m & 1) ? Wh : Wx) + (size_t)(m >> 1) * (HID * H4);

    __shared__ float tile[64][65];
    int c  = threadIdx.x & 63;
    int r0 = (threadIdx.x >> 6) * 16;
    for (int i = 0; i < 16; ++i) {
        int r = r0 + i;
        tile[r][c] = src[(size_t)(kt * 64 + r) * H4 + nt * 64 + c];
    }
    __syncthreads();
    int k  = threadIdx.x & 63;
    int n0 = (threadIdx.x >> 6) * 16;
    for (int i = 0; i < 16; ++i) {
        int n = n0 + i;
        WT[(size_t)m * (H4 * HID) + (size_t)(nt * 64 + n) * HID + kt * 64 + k] =
            f32_to_bf16(tile[k][n]);
    }
}

// ---- persistent LSTM kernel: 128 WGs x 1024 threads ----
__global__ __launch_bounds__(1024, 4) void lstm_persistent(
    const ushort* __restrict__ WT,   // [4][2048][512] bf16 (N-major, K contiguous)
    const ushort* __restrict__ xq,   // [512][64][512] bf16
    const float*  __restrict__ bh,   // [2][2048]
    u64*   __restrict__ h0T,         // [DEPTH][64][256] tagged records
    u64*   __restrict__ h1T,         // [DEPTH][64][256]
    float* __restrict__ out,         // d_out
    int*   __restrict__ f1prog)      // [4][16] L1 progress (throttle), zeroed
{
    const int wg    = blockIdx.x;        // 0..127
    const int layer = wg >> 6;
    const int quad  = (wg >> 4) & 3;
    const int strip = wg & 15;           // 32-column strip
    const int j0    = strip * 32;
    const int tid   = threadIdx.x;
    const int wave  = tid >> 6;          // 0..15
    const int lane  = tid & 63;
    const int g     = wave & 3;          // gate
    const int ch    = (wave >> 2) & 1;   // col-tile half (16 cols)
    const int kh    = wave >> 3;         // K half (0..1)
    const int lo    = lane & 15;
    const int hi    = lane >> 4;

    int* myprog = &f1prog[quad * NSTRIP + strip];   // only L1 publishes

    // weight fragment base pointers (gemm_bt layout, k contiguous-8/lane)
    const ushort* bx = WT + (size_t)(layer * 2 + 0) * (H4 * HID)
                     + (size_t)(g * 512 + j0 + ch * 16 + lo) * HID + kh * 256 + hi * 8;
    const ushort* bw = WT + (size_t)(layer * 2 + 1) * (H4 * HID)
                     + (size_t)(g * 512 + j0 + ch * 16 + lo) * HID + kh * 256 + hi * 8;
    bf16x8 wx[8], wh[8];
#pragma unroll
    for (int kk = 0; kk < 8; ++kk) {
        wx[kk] = *(const bf16x8*)(bx + kk * 32);
        wh[kk] = *(const bf16x8*)(bw + kk * 32);
    }
#pragma unroll
    for (int kk = 0; kk < 8; ++kk) {
        asm volatile("" : "+v"(wx[kk]));
        asm volatile("" : "+v"(wh[kk]));
    }

    // gate-phase mapping (threads 0..255): row = tid>>4 (0..15), cols cp,cp+1 (0..31)
    const int grow = tid >> 4;
    const int cp   = (tid & 15) * 2;
    f32x2 bias2[4];
#pragma unroll
    for (int gg = 0; gg < 4; ++gg)
        bias2[gg] = *(const f32x2*)&bh[layer * H4 + gg * 512 + j0 + cp];
    f32x2 creg = (f32x2)(0.f);

    __shared__ __align__(16) ushort ldsA[2][QR * HID];      // 32 KB: A1, A2 tiles
    __shared__ __align__(16) float  lds_g[4][2][QR][34];    // padded (32+2)

    // staging: 1024 threads, 8 bf16 per matrix: row = tid>>6, kba = tid&63
    const int row  = tid >> 6;             // 0..15
    const int kba  = tid & 63;
    const int goff  = (quad * QR + row) * HID + kba * 8;               // bf16 elems
    const int roff  = (quad * QR + row) * RPR + kba * 4;               // records
    const int laddr = ((row << 10) + (kba << 4)) ^ ((row & 15) << 4);
    const bf16x8 zero8 = {0, 0, 0, 0, 0, 0, 0, 0};

    for (int s = 0; s <= TSEQ; ++s) {
        const int t = s - layer;
        const bool active = (t >= 0 && t < TSEQ);

        if (active) {
            bf16x8 v0, v1;
            if (layer == 0) {
                // xq static: plain cached load (L2-hot)
                v0 = *(const bf16x8*)(xq + (size_t)t * BH + goff);
                // ring-overwrite throttle: L1 must be past s-6 (slack; rarely spins)
                if (s >= 6 && tid < NSTRIP) {
                    const int* f = &f1prog[quad * NSTRIP + tid];
                    while (__hip_atomic_load(f, __ATOMIC_RELAXED,
                                             __HIP_MEMORY_SCOPE_AGENT) < s - 6)
                        __builtin_amdgcn_s_sleep(1);
                }
                // self-recurrence h0[t-1]: tagged retry-load (tag = t)
                v1 = (t == 0) ? zero8
                              : load_tagged(h0T + (size_t)((t - 1) & 7) * (BATCH * RPR)
                                            + roff, (unsigned)t);
            } else {
                // h0[t]: tag t+1 (one stage of pipeline slack via skew)
                v0 = load_tagged(h0T + (size_t)(t & 7) * (BATCH * RPR) + roff,
                                 (unsigned)(t + 1));
                // self-recurrence h1[t-1]: tag t
                v1 = (t == 0) ? zero8
                              : load_tagged(h1T + (size_t)((t - 1) & 7) * (BATCH * RPR)
                                            + roff, (unsigned)t);
            }
            __builtin_amdgcn_sched_barrier(0);
            *(bf16x8*)((char*)&ldsA[0][0] + laddr) = v0;
            *(bf16x8*)((char*)&ldsA[1][0] + laddr) = v1;
            __syncthreads();                         // bar1: tiles staged

            // L1 progress publish (throttle only; no drain needed)
            if (layer == 1 && tid == 0)
                __hip_atomic_store(myprog, s, __ATOMIC_RELAXED,
                                   __HIP_MEMORY_SCOPE_AGENT);

            // MFMA: wave (g, ch, kh) computes 16x16 tile (cols ch*16), K-half kh
            f32x4 acc = (f32x4)(0.f);
#pragma unroll
            for (int kk = 0; kk < 8; ++kk) {
                const int kb2 = kh * 512 + kk * 64 + hi * 16;        // byte offset in row
                const int ad  = ((lo << 10) + kb2) ^ ((lo & 15) << 4);
                bf16x8 a1 = *(const bf16x8*)((char*)&ldsA[0][0] + ad);
                bf16x8 a2 = *(const bf16x8*)((char*)&ldsA[1][0] + ad);
                acc = __builtin_amdgcn_mfma_f32_16x16x32_bf16(a1, wx[kk], acc, 0, 0, 0);
                acc = __builtin_amdgcn_mfma_f32_16x16x32_bf16(a2, wh[kk], acc, 0, 0, 0);
            }
            // C/D layout: col = lane&15, row = (lane>>4)*4 + r
#pragma unroll
            for (int r = 0; r < 4; ++r)
                lds_g[g][kh][hi * 4 + r][ch * 16 + lo] = acc[r];
            __syncthreads();                         // bar2: partials ready

            // gates (threads 0..255): 2 cells per thread; publish tagged record
            if (tid < 256) {
                f32x2 gi = *(const f32x2*)&lds_g[0][0][grow][cp]
                         + *(const f32x2*)&lds_g[0][1][grow][cp] + bias2[0];
                f32x2 gf = *(const f32x2*)&lds_g[1][0][grow][cp]
                         + *(const f32x2*)&lds_g[1][1][grow][cp] + bias2[1];
                f32x2 gg = *(const f32x2*)&lds_g[2][0][grow][cp]
                         + *(const f32x2*)&lds_g[2][1][grow][cp] + bias2[2];
                f32x2 go = *(const f32x2*)&lds_g[3][0][grow][cp]
                         + *(const f32x2*)&lds_g[3][1][grow][cp] + bias2[3];
                f32x2 cn, hn;
#pragma unroll
                for (int q = 0; q < 2; ++q) {
                    float si = 1.f / (1.f + __expf(-gi[q]));
                    float sf = 1.f / (1.f + __expf(-gf[q]));
                    float so = 1.f / (1.f + __expf(-go[q]));
                    float tg = tanhf(gg[q]);
                    cn[q] = sf * creg[q] + si * tg;
                    hn[q] = so * tanhf(cn[q]);
                }
                creg = cn;

                unsigned hp = (unsigned)f32_to_bf16(hn[0])
                            | ((unsigned)f32_to_bf16(hn[1]) << 16);
                u64 rec = (u64)hp | ((u64)(unsigned)(t + 1) << 32);
                u64* hw = ((layer == 0) ? h0T : h1T)
                        + (size_t)(t & 7) * (BATCH * RPR)
                        + (size_t)(quad * QR + grow) * RPR + ((j0 + cp) >> 1);
                __hip_atomic_store(hw, rec, __ATOMIC_RELAXED,
                                   __HIP_MEMORY_SCOPE_AGENT);

                // out / finals (plain stores, off the handshake path)
                const int hoff = (quad * QR + grow) * HID + j0 + cp;
                if (layer == 1)
                    *(f32x2*)&out[(size_t)t * BH + hoff] = hn;
                if (t == TSEQ - 1) {
                    size_t base = (size_t)TSEQ * BH + (size_t)layer * BH + hoff;
                    *(f32x2*)&out[base] = hn;                       // h_fin
                    *(f32x2*)&out[base + 2 * (size_t)BH] = cn;      // c_fin
                }
            }
        } else {
            // inactive stage: L1 keeps progress monotone for the throttle
            if (layer == 1 && tid == 0)
                __hip_atomic_store(myprog, s, __ATOMIC_RELAXED,
                                   __HIP_MEMORY_SCOPE_AGENT);
            __syncthreads();
        }
    }
}

extern "C" void kernel_launch(void* const* d_in, const int* in_sizes, int n_in,
                              void* d_out, int out_size, void* d_ws, size_t ws_size,
                              hipStream_t stream) {
    const float* x  = (const float*)d_in[0];
    const float* Wh = (const float*)d_in[1];
    const float* Wx = (const float*)d_in[2];
    const float* bh = (const float*)d_in[3];
    float* out = (float*)d_out;

    char* ws = (char*)d_ws;
    // layout: WT 8MB | xq 32MB | h0T 1MB | h1T 1MB | f1prog  (~42MB total)
    ushort* WT = (ushort*)ws;
    ushort* xq = (ushort*)(ws + ((size_t)8 << 20));
    char* state = ws + ((size_t)8 << 20) + ((size_t)32 << 20);
    u64* h0T = (u64*)state;                                // [8][64][256] u64
    u64* h1T = h0T + (size_t)DEPTH * BATCH * RPR;
    int* f1prog = (int*)(h1T + (size_t)DEPTH * BATCH * RPR);   // [4][16]
    size_t clear_bytes = (size_t)2 * DEPTH * BATCH * RPR * sizeof(u64)
                       + 64 * sizeof(int);

    hipMemsetAsync(state, 0, clear_bytes, stream);  // zero tags + progress flags
    convert_x<<<2048, 256, 0, stream>>>(x, xq);
    transpose_w<<<1024, 256, 0, stream>>>(Wh, Wx, WT);
    lstm_persistent<<<128, 1024, 0, stream>>>(WT, xq, bh, h0T, h1T, out, f1prog);
}